// Round 8
// baseline (394.111 us; speedup 1.0000x reference)
//
#include <hip/hip_runtime.h>

// Window MHA: B=16, H=W=64, C=512, WS=8, NH=16, hd=32. f32 I/O.
// conv weights + maskT once; per chunk: conv_permute_x -> gemm_qkv (QK rowmajor
// + V transposed) -> attn (2 blk/CU, prefetched heads) -> gemm_proj.

typedef unsigned short u16;
typedef unsigned int u32;
typedef __attribute__((ext_vector_type(4))) u16 u16x4;
typedef __attribute__((ext_vector_type(8))) u16 u16x8;
typedef __attribute__((ext_vector_type(8))) short short8;
typedef __attribute__((ext_vector_type(4))) float f32x4;

__device__ __forceinline__ u16 f2bf(float f) {
    u32 u = __float_as_uint(f);
    u += 0x7fffu + ((u >> 16) & 1u);   // RNE
    return (u16)(u >> 16);
}

__device__ __forceinline__ f32x4 MFMA(u16x8 a, u16x8 b, f32x4 c) {
    return __builtin_amdgcn_mfma_f32_16x16x32_bf16(
        __builtin_bit_cast(short8, a), __builtin_bit_cast(short8, b), c, 0, 0, 0);
}

__device__ __forceinline__ void gload16(const void* g, void* l) {
    __builtin_amdgcn_global_load_lds(
        (const __attribute__((address_space(1))) void*)g,
        (__attribute__((address_space(3))) void*)l, 16, 0, 0);
}

// chunk-local window-order row -> image-order row
__device__ __forceinline__ int win2img(int r) {
    int b = r >> 12;
    int w = (r >> 6) & 63;
    int t = r & 63;
    int img = (((w >> 3) << 3) + (t >> 3)) * 64 + ((w & 7) << 3) + (t & 7);
    return (b << 12) + img;
}

__device__ __forceinline__ u16x8 cvt8(const float* src) {
    float4 a = *(const float4*)src;
    float4 b = *(const float4*)(src + 4);
    u16x8 t;
    t[0] = f2bf(a.x); t[1] = f2bf(a.y); t[2] = f2bf(a.z); t[3] = f2bf(a.w);
    t[4] = f2bf(b.x); t[5] = f2bf(b.y); t[6] = f2bf(b.z); t[7] = f2bf(b.w);
    return t;
}

__global__ __launch_bounds__(256)
void conv_f2b(const float* __restrict__ in, u16* __restrict__ out, int n8) {
    int u = blockIdx.x * 256 + threadIdx.x;
    if (u >= n8) return;
    *(u16x8*)(out + (size_t)u * 8) = cvt8(in + (size_t)u * 8);
}

__global__ __launch_bounds__(256)
void conv_permute_x(const float* __restrict__ x, u16* __restrict__ xw) {
    int u = blockIdx.x * 256 + threadIdx.x;   // unit = 8 elems
    int r = u >> 6;                           // window-order row
    int c = (u & 63) << 3;
    int g = win2img(r);
    *(u16x8*)(xw + (size_t)r * 512 + c) = cvt8(x + (size_t)g * 512 + c);
}

// mask [64][q 64][k 64] f32 -> mT [64][k 64][q 64] f32 (1 MB, once)
__global__ __launch_bounds__(256)
void conv_maskT(const float* __restrict__ mask, float* __restrict__ mT) {
    __shared__ float t[64][65];
    const int w = blockIdx.x;
    const float* mp = mask + ((size_t)w << 12);
    float* op = mT + ((size_t)w << 12);
    const int r = threadIdx.x >> 2, c0 = (threadIdx.x & 3) << 4;
#pragma unroll
    for (int i = 0; i < 4; ++i) {
        float4 v = *(const float4*)(mp + (r << 6) + c0 + i * 4);
        t[c0 + i * 4 + 0][r] = v.x;
        t[c0 + i * 4 + 1][r] = v.y;
        t[c0 + i * 4 + 2][r] = v.z;
        t[c0 + i * 4 + 3][r] = v.w;
    }
    __syncthreads();
#pragma unroll
    for (int i = 0; i < 4; ++i) {
        float4 v;
        v.x = t[r][c0 + i * 4 + 0];
        v.y = t[r][c0 + i * 4 + 1];
        v.z = t[r][c0 + i * 4 + 2];
        v.w = t[r][c0 + i * 4 + 3];
        *(float4*)(op + (r << 6) + c0 + i * 4) = v;
    }
}

// ---- QKV GEMM (round-4 verified 2-phase): A=xw bf16 window-order ----
// cols 0..1023 -> QK[row][1024]; cols 1024..1535 -> VT[win][d][64].
__global__ __launch_bounds__(256, 4)
void gemm_qkv(const u16* __restrict__ A, const u16* __restrict__ Wt,
              const float* __restrict__ bias, u16* __restrict__ QK,
              u16* __restrict__ VT)
{
    __shared__ char lds[32768];   // [buf:2][A 8KB | B 8KB]

    const int nwg = gridDim.x;            // % 8 == 0
    const int q   = nwg >> 3;
    const int wg  = ((int)blockIdx.x & 7) * q + ((int)blockIdx.x >> 3);
    const int m0  = (wg / 12) * 128;
    const int n0  = (wg % 12) * 128;      // N-fastest: A-panel L2 reuse

    const int tid  = threadIdx.x;
    const int lane = tid & 63;
    const int wv   = tid >> 6;
    const int wm   = (wv >> 1) << 6;
    const int wn   = (wv & 1) << 6;
    const int lr   = lane & 15;
    const int lg   = lane >> 4;

    const char* aptr = (const char*)A + (((size_t)(m0 + (tid >> 2))) << 10) + ((tid & 3) << 4);
    const char* bptr = (const char*)Wt + (((size_t)(n0 + (tid >> 2))) << 10) + ((tid & 3) << 4);
    const u32 tb = (u32)tid << 4;

    f32x4 acc[4][4] = {};

#define STAGE(buf, kt) do {                                                   \
    const int ko_ = (kt) * 64;                                                \
    char* d_ = lds + (buf) * 16384 + tb;                                      \
    gload16(aptr + ko_,              d_);                                     \
    gload16(aptr + (64 << 10) + ko_, d_ + 4096);                              \
    gload16(bptr + ko_,              d_ + 8192);                              \
    gload16(bptr + (64 << 10) + ko_, d_ + 12288);                             \
} while (0)

#define COMPUTE(buf) do {                                                     \
    const u16* As_ = (const u16*)(lds + (buf) * 16384);                       \
    const u16* Bs_ = (const u16*)(lds + (buf) * 16384 + 8192);                \
    u16x8 af_[4], bf_[4];                                                     \
    _Pragma("unroll")                                                         \
    for (int mi = 0; mi < 4; ++mi)                                            \
        af_[mi] = *(const u16x8*)(As_ + (wm + mi * 16 + lr) * 32 + lg * 8);   \
    _Pragma("unroll")                                                         \
    for (int ni = 0; ni < 4; ++ni)                                            \
        bf_[ni] = *(const u16x8*)(Bs_ + (wn + ni * 16 + lr) * 32 + lg * 8);   \
    _Pragma("unroll")                                                         \
    for (int mi = 0; mi < 4; ++mi)                                            \
        _Pragma("unroll")                                                     \
        for (int ni = 0; ni < 4; ++ni)                                        \
            acc[mi][ni] = MFMA(af_[mi], bf_[ni], acc[mi][ni]);                \
} while (0)

    STAGE(0, 0);
    __syncthreads();

#pragma unroll 1
    for (int kt = 0; kt < 16; kt += 2) {
        STAGE(1, kt + 1);
        COMPUTE(0);
        __syncthreads();
        if (kt + 2 < 16) STAGE(0, kt + 2);
        COMPUTE(1);
        __syncthreads();
    }

    if (n0 < 1024) {
#pragma unroll
        for (int mi = 0; mi < 4; ++mi)
#pragma unroll
            for (int ni = 0; ni < 4; ++ni) {
                const int col = n0 + wn + ni * 16 + lr;
                const float bv = bias[col];
#pragma unroll
                for (int r = 0; r < 4; ++r) {
                    const int gr = m0 + wm + mi * 16 + lg * 4 + r;
                    QK[((size_t)gr << 10) + col] = f2bf(acc[mi][ni][r] + bv);
                }
            }
    } else {
#pragma unroll
        for (int mi = 0; mi < 4; ++mi) {
            const int gr0 = m0 + wm + mi * 16 + lg * 4;
            const int win = gr0 >> 6, ro = gr0 & 63;
#pragma unroll
            for (int ni = 0; ni < 4; ++ni) {
                const int col = n0 + wn + ni * 16 + lr;
                const float bv = bias[col];
                const int d = col - 1024;
                u16x4 h;
#pragma unroll
                for (int r = 0; r < 4; ++r) h[r] = f2bf(acc[mi][ni][r] + bv);
                *(u16x4*)(VT + (((size_t)win << 9) + d) * 64 + ro) = h;
            }
        }
    }
}

// ---- proj GEMM (round-4 structure): bf16 A, f32 out + window reverse ----
__global__ __launch_bounds__(256, 4)
void gemm_proj(const u16* __restrict__ A, const u16* __restrict__ Wt,
               const float* __restrict__ bias, float* __restrict__ C)
{
    __shared__ char lds[32768];

    const int nwg = gridDim.x;    // % 8 == 0
    const int q   = nwg >> 3;
    const int wg  = ((int)blockIdx.x & 7) * q + ((int)blockIdx.x >> 3);
    const int m0  = (wg / 4) * 128;
    const int n0  = (wg % 4) * 128;

    const int tid  = threadIdx.x;
    const int lane = tid & 63;
    const int wv   = tid >> 6;
    const int wm   = (wv >> 1) << 6;
    const int wn   = (wv & 1) << 6;
    const int lr   = lane & 15;
    const int lg   = lane >> 4;

    const char* aptr = (const char*)A + (((size_t)(m0 + (tid >> 2))) << 10) + ((tid & 3) << 4);
    const char* bptr = (const char*)Wt + (((size_t)(n0 + (tid >> 2))) << 10) + ((tid & 3) << 4);
    const u32 tb = (u32)tid << 4;

    f32x4 acc[4][4] = {};

    STAGE(0, 0);
    __syncthreads();

#pragma unroll 1
    for (int kt = 0; kt < 16; kt += 2) {
        STAGE(1, kt + 1);
        COMPUTE(0);
        __syncthreads();
        if (kt + 2 < 16) STAGE(0, kt + 2);
        COMPUTE(1);
        __syncthreads();
    }

#undef STAGE
#undef COMPUTE

#pragma unroll
    for (int mi = 0; mi < 4; ++mi)
#pragma unroll
        for (int ni = 0; ni < 4; ++ni) {
            const int col = n0 + wn + ni * 16 + lr;
            const float bv = bias[col];
#pragma unroll
            for (int r = 0; r < 4; ++r) {
                const int gr = win2img(m0 + wm + mi * 16 + lg * 4 + r);
                C[((size_t)gr << 9) + col] = acc[mi][ni][r] + bv;
            }
        }
}

// ---- attention: one block per window; 4 waves x 4 heads; head prefetch ----
// QK: [rows][1024] bf16. VT: [win][512][64] bf16. mT: [64][k][q] f32.
__global__ __launch_bounds__(256, 2)
void attn_kernel(const u16* __restrict__ QK, const u16* __restrict__ VT,
                 const float* __restrict__ mT, u16* __restrict__ attn_out)
{
    __shared__ __align__(16) u16 sP[4][64][72];   // 73.7 KB -> 2 blocks/CU

    const int tid  = threadIdx.x;
    const int lane = tid & 63;
    const int wv   = tid >> 6;
    const int lr   = lane & 15;
    const int lg   = lane >> 4;
    const int win  = blockIdx.x;
    const int wib  = win & 63;
    const size_t rb = (size_t)win << 6;
    const float* mtp = mT + ((size_t)wib << 12);
    const u16* vbase = VT + ((size_t)win << 15);
    const float scale = 0.17677669529663687f;   // 32^-0.5

    u16x8 qf[2][4], kf[2][4], vf[2][2][2];

#define LOADH(hi_, b_) do {                                                   \
    const int hoff_ = ((hi_) * 4 + wv) * 32;                                  \
    _Pragma("unroll") for (int mt = 0; mt < 4; ++mt) {                        \
        const u16* rp_ = QK + ((rb + mt * 16 + lr) << 10) + hoff_ + lg * 8;   \
        qf[b_][mt] = *(const u16x8*)rp_;                                      \
        kf[b_][mt] = *(const u16x8*)(rp_ + 512);                              \
    }                                                                         \
    _Pragma("unroll") for (int k2_ = 0; k2_ < 2; ++k2_)                       \
    _Pragma("unroll") for (int nt_ = 0; nt_ < 2; ++nt_)                       \
        vf[b_][k2_][nt_] = *(const u16x8*)(vbase                              \
            + ((size_t)(hoff_ + nt_ * 16 + lr) << 6) + k2_ * 32 + lg * 8);    \
} while (0)

    LOADH(0, 0);

#pragma unroll
    for (int hi = 0; hi < 4; ++hi) {
        const int cb = hi & 1;
        const int hoff = (hi * 4 + wv) * 32;

        // ---- S = Q K^T ----
        f32x4 s[4][4] = {};
#pragma unroll
        for (int mi = 0; mi < 4; ++mi)
#pragma unroll
            for (int ni = 0; ni < 4; ++ni)
                s[mi][ni] = MFMA(qf[cb][mi], kf[cb][ni], s[mi][ni]);

        if (hi < 3) LOADH(hi + 1, cb ^ 1);   // fly under softmax + barriers

        // ---- scale + mask + softmax ----
        float rsum[4][4];
#pragma unroll
        for (int mi = 0; mi < 4; ++mi) {
            float4 mv[4];
#pragma unroll
            for (int ni = 0; ni < 4; ++ni)
                mv[ni] = *(const float4*)(mtp + (ni * 16 + lr) * 64 + mi * 16 + lg * 4);
#pragma unroll
            for (int r = 0; r < 4; ++r) {
                float vv[4];
                float mx = -1e30f;
#pragma unroll
                for (int ni = 0; ni < 4; ++ni) {
                    float v = s[mi][ni][r] * scale + ((const float*)&mv[ni])[r];
                    vv[ni] = v;
                    mx = fmaxf(mx, v);
                }
#pragma unroll
                for (int mk = 1; mk <= 8; mk <<= 1)
                    mx = fmaxf(mx, __shfl_xor(mx, mk, 64));
                float sum = 0.f;
#pragma unroll
                for (int ni = 0; ni < 4; ++ni) {
                    float p = __expf(vv[ni] - mx);
                    sum += p;
                    s[mi][ni][r] = p;
                }
#pragma unroll
                for (int mk = 1; mk <= 8; mk <<= 1)
                    sum += __shfl_xor(sum, mk, 64);
                rsum[mi][r] = sum;
            }
        }

        __syncthreads();
#pragma unroll
        for (int mi = 0; mi < 4; ++mi)
#pragma unroll
            for (int ni = 0; ni < 4; ++ni)
#pragma unroll
                for (int r = 0; r < 4; ++r)
                    sP[wv][mi * 16 + lg * 4 + r][ni * 16 + lr] = f2bf(s[mi][ni][r]);
        __syncthreads();

        // ---- O = P V ----
        u16x8 pf[4][2];
#pragma unroll
        for (int mt = 0; mt < 4; ++mt)
#pragma unroll
            for (int k2 = 0; k2 < 2; ++k2)
                pf[mt][k2] = *(const u16x8*)&sP[wv][mt * 16 + lr][k2 * 32 + lg * 8];

        f32x4 o[4][2] = {};
#pragma unroll
        for (int mt = 0; mt < 4; ++mt)
#pragma unroll
            for (int k2 = 0; k2 < 2; ++k2)
#pragma unroll
                for (int nt = 0; nt < 2; ++nt)
                    o[mt][nt] = MFMA(pf[mt][k2], vf[cb][k2][nt], o[mt][nt]);

#pragma unroll
        for (int mt = 0; mt < 4; ++mt)
#pragma unroll
            for (int nt = 0; nt < 2; ++nt)
#pragma unroll
                for (int r = 0; r < 4; ++r) {
                    const int row = mt * 16 + lg * 4 + r;
                    const int d = nt * 16 + lr;
                    attn_out[((rb + row) << 9) + hoff + d] =
                        f2bf(o[mt][nt][r] / rsum[mt][r]);
                }
    }
#undef LOADH
}

extern "C" void kernel_launch(void* const* d_in, const int* in_sizes, int n_in,
                              void* d_out, int out_size, void* d_ws, size_t ws_size,
                              hipStream_t stream)
{
    const float* x      = (const float*)d_in[0];
    const float* qkv_w  = (const float*)d_in[1];
    const float* qkv_b  = (const float*)d_in[2];
    const float* proj_w = (const float*)d_in[3];
    const float* proj_b = (const float*)d_in[4];
    const float* mask   = (const float*)d_in[5];
    float* out = (float*)d_out;

    const size_t WQKV  = 1536ull * 512;
    const size_t WPROJ = 512ull * 512;
    const size_t MTSZ  = 64ull * 64 * 64;   // f32 elems

    u16* wq = (u16*)d_ws;
    u16* wp = wq + WQKV;
    float* mTg = (float*)(wp + WPROJ);
    u16* chunk = (u16*)(mTg + MTSZ);

    const size_t xwPB  = 4096ull * 512;
    const size_t qkPB  = 4096ull * 1024;
    const size_t vtPB  = 4096ull * 512;
    const size_t attPB = 4096ull * 512;
    const size_t perBatchBytes = (xwPB + qkPB + vtPB + attPB) * 2;

    size_t avail = ws_size - (WQKV + WPROJ) * 2 - MTSZ * 4;
    int Bc = (int)(avail / perBatchBytes);
    if (Bc > 16) Bc = 16;
    if (Bc < 1) Bc = 1;

    u16* xw_ws  = chunk;
    u16* qk_ws  = xw_ws + (size_t)Bc * xwPB;
    u16* vt_ws  = qk_ws + (size_t)Bc * qkPB;
    u16* att_ws = vt_ws + (size_t)Bc * vtPB;

    conv_f2b<<<dim3((WQKV / 8 + 255) / 256), 256, 0, stream>>>(qkv_w, wq, (int)(WQKV / 8));
    conv_f2b<<<dim3((WPROJ / 8 + 255) / 256), 256, 0, stream>>>(proj_w, wp, (int)(WPROJ / 8));
    conv_maskT<<<dim3(64), 256, 0, stream>>>(mask, mTg);

    for (int b0 = 0; b0 < 16; b0 += Bc) {
        const int bc = (16 - b0) < Bc ? (16 - b0) : Bc;
        const float* xc = x + (size_t)b0 * 4096 * 512;
        float* outc = out + (size_t)b0 * 4096 * 512;

        conv_permute_x<<<dim3(bc * 1024), 256, 0, stream>>>(xc, xw_ws);
        gemm_qkv<<<dim3(bc * 32 * 12), 256, 0, stream>>>(
            xw_ws, wq, qkv_b, qk_ws, vt_ws);
        attn_kernel<<<dim3(bc * 64), 256, 0, stream>>>(
            qk_ws, vt_ws, mTg, att_ws);
        gemm_proj<<<dim3(bc * 32 * 4), 256, 0, stream>>>(
            att_ws, wp, proj_b, outc);
    }
}

// Round 9
// 338.900 us; speedup vs baseline: 1.1629x; 1.1629x over previous
//
#include <hip/hip_runtime.h>

// Window MHA: B=16, H=W=64, C=512, WS=8, NH=16, hd=32. f32 I/O.
// conv weights + maskT once; per chunk: conv_permute_x -> gemm_qkv (writes
// head-blocked Q/K + transposed V) -> attn (coalesced frags) -> gemm_proj.

typedef unsigned short u16;
typedef unsigned int u32;
typedef __attribute__((ext_vector_type(4))) u16 u16x4;
typedef __attribute__((ext_vector_type(8))) u16 u16x8;
typedef __attribute__((ext_vector_type(8))) short short8;
typedef __attribute__((ext_vector_type(4))) float f32x4;

__device__ __forceinline__ u16 f2bf(float f) {
    u32 u = __float_as_uint(f);
    u += 0x7fffu + ((u >> 16) & 1u);   // RNE
    return (u16)(u >> 16);
}

__device__ __forceinline__ f32x4 MFMA(u16x8 a, u16x8 b, f32x4 c) {
    return __builtin_amdgcn_mfma_f32_16x16x32_bf16(
        __builtin_bit_cast(short8, a), __builtin_bit_cast(short8, b), c, 0, 0, 0);
}

__device__ __forceinline__ void gload16(const void* g, void* l) {
    __builtin_amdgcn_global_load_lds(
        (const __attribute__((address_space(1))) void*)g,
        (__attribute__((address_space(3))) void*)l, 16, 0, 0);
}

// chunk-local window-order row -> image-order row
__device__ __forceinline__ int win2img(int r) {
    int b = r >> 12;
    int w = (r >> 6) & 63;
    int t = r & 63;
    int img = (((w >> 3) << 3) + (t >> 3)) * 64 + ((w & 7) << 3) + (t & 7);
    return (b << 12) + img;
}

__device__ __forceinline__ u16x8 cvt8(const float* src) {
    float4 a = *(const float4*)src;
    float4 b = *(const float4*)(src + 4);
    u16x8 t;
    t[0] = f2bf(a.x); t[1] = f2bf(a.y); t[2] = f2bf(a.z); t[3] = f2bf(a.w);
    t[4] = f2bf(b.x); t[5] = f2bf(b.y); t[6] = f2bf(b.z); t[7] = f2bf(b.w);
    return t;
}

__global__ __launch_bounds__(256)
void conv_f2b(const float* __restrict__ in, u16* __restrict__ out, int n8) {
    int u = blockIdx.x * 256 + threadIdx.x;
    if (u >= n8) return;
    *(u16x8*)(out + (size_t)u * 8) = cvt8(in + (size_t)u * 8);
}

__global__ __launch_bounds__(256)
void conv_permute_x(const float* __restrict__ x, u16* __restrict__ xw) {
    int u = blockIdx.x * 256 + threadIdx.x;   // unit = 8 elems
    int r = u >> 6;                           // window-order row
    int c = (u & 63) << 3;
    int g = win2img(r);
    *(u16x8*)(xw + (size_t)r * 512 + c) = cvt8(x + (size_t)g * 512 + c);
}

// mask [64][q 64][k 64] f32 -> mT [64][k 64][q 64] f32 (1 MB, once)
__global__ __launch_bounds__(256)
void conv_maskT(const float* __restrict__ mask, float* __restrict__ mT) {
    __shared__ float t[64][65];
    const int w = blockIdx.x;
    const float* mp = mask + ((size_t)w << 12);
    float* op = mT + ((size_t)w << 12);
    const int r = threadIdx.x >> 2, c0 = (threadIdx.x & 3) << 4;
#pragma unroll
    for (int i = 0; i < 4; ++i) {
        float4 v = *(const float4*)(mp + (r << 6) + c0 + i * 4);
        t[c0 + i * 4 + 0][r] = v.x;
        t[c0 + i * 4 + 1][r] = v.y;
        t[c0 + i * 4 + 2][r] = v.z;
        t[c0 + i * 4 + 3][r] = v.w;
    }
    __syncthreads();
#pragma unroll
    for (int i = 0; i < 4; ++i) {
        float4 v;
        v.x = t[r][c0 + i * 4 + 0];
        v.y = t[r][c0 + i * 4 + 1];
        v.z = t[r][c0 + i * 4 + 2];
        v.w = t[r][c0 + i * 4 + 3];
        *(float4*)(op + (r << 6) + c0 + i * 4) = v;
    }
}

// ---- shared 2-phase GEMM macros (capture local names) ----
#define STAGE(buf, kt) do {                                                   \
    const int ko_ = (kt) * 64;                                                \
    char* d_ = lds + (buf) * 16384 + tb;                                      \
    gload16(aptr + ko_,              d_);                                     \
    gload16(aptr + (64 << 10) + ko_, d_ + 4096);                              \
    gload16(bptr + ko_,              d_ + 8192);                              \
    gload16(bptr + (64 << 10) + ko_, d_ + 12288);                             \
} while (0)

#define COMPUTE(buf) do {                                                     \
    const u16* As_ = (const u16*)(lds + (buf) * 16384);                       \
    const u16* Bs_ = (const u16*)(lds + (buf) * 16384 + 8192);                \
    u16x8 af_[4], bf_[4];                                                     \
    _Pragma("unroll")                                                         \
    for (int mi = 0; mi < 4; ++mi)                                            \
        af_[mi] = *(const u16x8*)(As_ + (wm + mi * 16 + lr) * 32 + lg * 8);   \
    _Pragma("unroll")                                                         \
    for (int ni = 0; ni < 4; ++ni)                                            \
        bf_[ni] = *(const u16x8*)(Bs_ + (wn + ni * 16 + lr) * 32 + lg * 8);   \
    _Pragma("unroll")                                                         \
    for (int mi = 0; mi < 4; ++mi)                                            \
        _Pragma("unroll")                                                     \
        for (int ni = 0; ni < 4; ++ni)                                        \
            acc[mi][ni] = MFMA(af_[mi], bf_[ni], acc[mi][ni]);                \
} while (0)

// ---- QKV GEMM (round-4 2-phase). Epilogue: head-blocked Q/K + VT ----
// QH/KH: [win][h][64][32] bf16. VT: [win][d 512][64] bf16.
__global__ __launch_bounds__(256, 4)
void gemm_qkv(const u16* __restrict__ A, const u16* __restrict__ Wt,
              const float* __restrict__ bias, u16* __restrict__ QH,
              u16* __restrict__ KH, u16* __restrict__ VT)
{
    __shared__ char lds[32768];

    const int nwg = gridDim.x;            // % 8 == 0
    const int q   = nwg >> 3;
    const int wg  = ((int)blockIdx.x & 7) * q + ((int)blockIdx.x >> 3);
    const int m0  = (wg / 12) * 128;
    const int n0  = (wg % 12) * 128;      // N-fastest: A-panel L2 reuse

    const int tid  = threadIdx.x;
    const int lane = tid & 63;
    const int wv   = tid >> 6;
    const int wm   = (wv >> 1) << 6;
    const int wn   = (wv & 1) << 6;
    const int lr   = lane & 15;
    const int lg   = lane >> 4;

    const char* aptr = (const char*)A + (((size_t)(m0 + (tid >> 2))) << 10) + ((tid & 3) << 4);
    const char* bptr = (const char*)Wt + (((size_t)(n0 + (tid >> 2))) << 10) + ((tid & 3) << 4);
    const u32 tb = (u32)tid << 4;

    f32x4 acc[4][4] = {};

    STAGE(0, 0);
    __syncthreads();

#pragma unroll 1
    for (int kt = 0; kt < 16; kt += 2) {
        STAGE(1, kt + 1);
        COMPUTE(0);
        __syncthreads();
        if (kt + 2 < 16) STAGE(0, kt + 2);
        COMPUTE(1);
        __syncthreads();
    }

    if (n0 < 1024) {
        u16* __restrict__ P = (n0 < 512) ? QH : KH;
        const int cbase = (n0 < 512) ? n0 : (n0 - 512);
#pragma unroll
        for (int mi = 0; mi < 4; ++mi) {
            const int gr0 = m0 + wm + mi * 16 + lg * 4;
            const int win = gr0 >> 6, ro = gr0 & 63;
#pragma unroll
            for (int ni = 0; ni < 4; ++ni) {
                const int col = cbase + wn + ni * 16 + lr;
                const float bv = bias[(n0 < 512) ? col : (col + 512)];
                const int h = col >> 5, c = col & 31;
                u16* dst = P + (((size_t)win * 16 + h) << 11) + (ro << 5) + c;
#pragma unroll
                for (int r = 0; r < 4; ++r)
                    dst[r << 5] = f2bf(acc[mi][ni][r] + bv);
            }
        }
    } else {
#pragma unroll
        for (int mi = 0; mi < 4; ++mi) {
            const int gr0 = m0 + wm + mi * 16 + lg * 4;
            const int win = gr0 >> 6, ro = gr0 & 63;
#pragma unroll
            for (int ni = 0; ni < 4; ++ni) {
                const int col = n0 + wn + ni * 16 + lr;
                const float bv = bias[col];
                const int d = col - 1024;
                u16x4 h;
#pragma unroll
                for (int r = 0; r < 4; ++r) h[r] = f2bf(acc[mi][ni][r] + bv);
                *(u16x4*)(VT + (((size_t)win << 9) + d) * 64 + ro) = h;
            }
        }
    }
}

// ---- proj GEMM (round-4 structure): bf16 A, f32 out + window reverse ----
__global__ __launch_bounds__(256, 4)
void gemm_proj(const u16* __restrict__ A, const u16* __restrict__ Wt,
               const float* __restrict__ bias, float* __restrict__ C)
{
    __shared__ char lds[32768];

    const int nwg = gridDim.x;    // % 8 == 0
    const int q   = nwg >> 3;
    const int wg  = ((int)blockIdx.x & 7) * q + ((int)blockIdx.x >> 3);
    const int m0  = (wg / 4) * 128;
    const int n0  = (wg % 4) * 128;

    const int tid  = threadIdx.x;
    const int lane = tid & 63;
    const int wv   = tid >> 6;
    const int wm   = (wv >> 1) << 6;
    const int wn   = (wv & 1) << 6;
    const int lr   = lane & 15;
    const int lg   = lane >> 4;

    const char* aptr = (const char*)A + (((size_t)(m0 + (tid >> 2))) << 10) + ((tid & 3) << 4);
    const char* bptr = (const char*)Wt + (((size_t)(n0 + (tid >> 2))) << 10) + ((tid & 3) << 4);
    const u32 tb = (u32)tid << 4;

    f32x4 acc[4][4] = {};

    STAGE(0, 0);
    __syncthreads();

#pragma unroll 1
    for (int kt = 0; kt < 16; kt += 2) {
        STAGE(1, kt + 1);
        COMPUTE(0);
        __syncthreads();
        if (kt + 2 < 16) STAGE(0, kt + 2);
        COMPUTE(1);
        __syncthreads();
    }

#pragma unroll
    for (int mi = 0; mi < 4; ++mi)
#pragma unroll
        for (int ni = 0; ni < 4; ++ni) {
            const int col = n0 + wn + ni * 16 + lr;
            const float bv = bias[col];
#pragma unroll
            for (int r = 0; r < 4; ++r) {
                const int gr = win2img(m0 + wm + mi * 16 + lg * 4 + r);
                C[((size_t)gr << 9) + col] = acc[mi][ni][r] + bv;
            }
        }
}

#undef STAGE
#undef COMPUTE

// ---- attention: one block per window; 4 waves x 4 heads each ----
// QH/KH: [win][h][64][32] bf16 (coalesced frag loads). VT: [win][d][64].
// mT: [win%64][k][q] f32. attn_out: [rows][512] bf16.
__global__ __launch_bounds__(256, 3)
void attn_kernel(const u16* __restrict__ QH, const u16* __restrict__ KH,
                 const u16* __restrict__ VT, const float* __restrict__ mT,
                 u16* __restrict__ attn_out)
{
    __shared__ __align__(16) u16 sP[4][64][72];   // 36.8 KB

    const int tid  = threadIdx.x;
    const int lane = tid & 63;
    const int wv   = tid >> 6;
    const int lr   = lane & 15;
    const int lg   = lane >> 4;
    const int win  = blockIdx.x;
    const int wib  = win & 63;
    const size_t rb = (size_t)win << 6;
    const float* mtp = mT + ((size_t)wib << 12);
    const u16* qbase = QH + ((size_t)win << 15);
    const u16* kbase = KH + ((size_t)win << 15);
    const u16* vbase = VT + ((size_t)win << 15);
    const float scale = 0.17677669529663687f;   // 32^-0.5

#pragma unroll 1
    for (int hi = 0; hi < 4; ++hi) {
        const int h = hi * 4 + wv;
        const int hoff = h * 32;
        const u16* qh = qbase + (h << 11);
        const u16* kh = kbase + (h << 11);

        // ---- S = Q K^T (fully coalesced fragment loads) ----
        u16x8 qf[4], kf[4];
#pragma unroll
        for (int mt = 0; mt < 4; ++mt) {
            const int off = ((mt * 16 + lr) << 5) + (lg << 3);
            qf[mt] = *(const u16x8*)(qh + off);
            kf[mt] = *(const u16x8*)(kh + off);
        }
        f32x4 s[4][4] = {};
#pragma unroll
        for (int mi = 0; mi < 4; ++mi)
#pragma unroll
            for (int ni = 0; ni < 4; ++ni)
                s[mi][ni] = MFMA(qf[mi], kf[ni], s[mi][ni]);

        // ---- scale + mask + softmax ----
        float rsum[4][4];
#pragma unroll
        for (int mi = 0; mi < 4; ++mi) {
            float4 mv[4];
#pragma unroll
            for (int ni = 0; ni < 4; ++ni)
                mv[ni] = *(const float4*)(mtp + (ni * 16 + lr) * 64 + mi * 16 + lg * 4);
#pragma unroll
            for (int r = 0; r < 4; ++r) {
                float vv[4];
                float mx = -1e30f;
#pragma unroll
                for (int ni = 0; ni < 4; ++ni) {
                    float v = s[mi][ni][r] * scale + ((const float*)&mv[ni])[r];
                    vv[ni] = v;
                    mx = fmaxf(mx, v);
                }
#pragma unroll
                for (int mk = 1; mk <= 8; mk <<= 1)
                    mx = fmaxf(mx, __shfl_xor(mx, mk, 64));
                float sum = 0.f;
#pragma unroll
                for (int ni = 0; ni < 4; ++ni) {
                    float p = __expf(vv[ni] - mx);
                    sum += p;
                    s[mi][ni][r] = p;
                }
#pragma unroll
                for (int mk = 1; mk <= 8; mk <<= 1)
                    sum += __shfl_xor(sum, mk, 64);
                rsum[mi][r] = sum;
            }
        }

        __syncthreads();
#pragma unroll
        for (int mi = 0; mi < 4; ++mi)
#pragma unroll
            for (int ni = 0; ni < 4; ++ni)
#pragma unroll
                for (int r = 0; r < 4; ++r)
                    sP[wv][mi * 16 + lg * 4 + r][ni * 16 + lr] = f2bf(s[mi][ni][r]);
        __syncthreads();

        // ---- O = P V ----
        u16x8 pf[4][2];
#pragma unroll
        for (int mt = 0; mt < 4; ++mt)
#pragma unroll
            for (int k2 = 0; k2 < 2; ++k2)
                pf[mt][k2] = *(const u16x8*)&sP[wv][mt * 16 + lr][k2 * 32 + lg * 8];

        u16x8 vf[2][2];
#pragma unroll
        for (int k2 = 0; k2 < 2; ++k2)
#pragma unroll
            for (int nt = 0; nt < 2; ++nt)
                vf[k2][nt] = *(const u16x8*)(vbase
                    + ((size_t)(hoff + nt * 16 + lr) << 6) + k2 * 32 + lg * 8);

        f32x4 o[4][2] = {};
#pragma unroll
        for (int mt = 0; mt < 4; ++mt)
#pragma unroll
            for (int k2 = 0; k2 < 2; ++k2)
#pragma unroll
                for (int nt = 0; nt < 2; ++nt)
                    o[mt][nt] = MFMA(pf[mt][k2], vf[k2][nt], o[mt][nt]);

#pragma unroll
        for (int mt = 0; mt < 4; ++mt)
#pragma unroll
            for (int nt = 0; nt < 2; ++nt)
#pragma unroll
                for (int r = 0; r < 4; ++r) {
                    const int row = mt * 16 + lg * 4 + r;
                    const int d = nt * 16 + lr;
                    attn_out[((rb + row) << 9) + hoff + d] =
                        f2bf(o[mt][nt][r] / rsum[mt][r]);
                }
    }
}

extern "C" void kernel_launch(void* const* d_in, const int* in_sizes, int n_in,
                              void* d_out, int out_size, void* d_ws, size_t ws_size,
                              hipStream_t stream)
{
    const float* x      = (const float*)d_in[0];
    const float* qkv_w  = (const float*)d_in[1];
    const float* qkv_b  = (const float*)d_in[2];
    const float* proj_w = (const float*)d_in[3];
    const float* proj_b = (const float*)d_in[4];
    const float* mask   = (const float*)d_in[5];
    float* out = (float*)d_out;

    const size_t WQKV  = 1536ull * 512;
    const size_t WPROJ = 512ull * 512;
    const size_t MTSZ  = 64ull * 64 * 64;   // f32 elems

    u16* wq = (u16*)d_ws;
    u16* wp = wq + WQKV;
    float* mTg = (float*)(wp + WPROJ);
    u16* chunk = (u16*)(mTg + MTSZ);

    const size_t xwPB  = 4096ull * 512;
    const size_t qhPB  = 4096ull * 512;    // [64 win][16 h][64][32]
    const size_t khPB  = 4096ull * 512;
    const size_t vtPB  = 4096ull * 512;
    const size_t attPB = 4096ull * 512;
    const size_t perBatchBytes = (xwPB + qhPB + khPB + vtPB + attPB) * 2;

    size_t avail = ws_size - (WQKV + WPROJ) * 2 - MTSZ * 4;
    int Bc = (int)(avail / perBatchBytes);
    if (Bc > 16) Bc = 16;
    if (Bc < 1) Bc = 1;

    u16* xw_ws  = chunk;
    u16* qh_ws  = xw_ws + (size_t)Bc * xwPB;
    u16* kh_ws  = qh_ws + (size_t)Bc * qhPB;
    u16* vt_ws  = kh_ws + (size_t)Bc * khPB;
    u16* att_ws = vt_ws + (size_t)Bc * vtPB;

    conv_f2b<<<dim3((WQKV / 8 + 255) / 256), 256, 0, stream>>>(qkv_w, wq, (int)(WQKV / 8));
    conv_f2b<<<dim3((WPROJ / 8 + 255) / 256), 256, 0, stream>>>(proj_w, wp, (int)(WPROJ / 8));
    conv_maskT<<<dim3(64), 256, 0, stream>>>(mask, mTg);

    for (int b0 = 0; b0 < 16; b0 += Bc) {
        const int bc = (16 - b0) < Bc ? (16 - b0) : Bc;
        const float* xc = x + (size_t)b0 * 4096 * 512;
        float* outc = out + (size_t)b0 * 4096 * 512;

        conv_permute_x<<<dim3(bc * 1024), 256, 0, stream>>>(xc, xw_ws);
        gemm_qkv<<<dim3(bc * 32 * 12), 256, 0, stream>>>(
            xw_ws, wq, qkv_b, qh_ws, kh_ws, vt_ws);
        attn_kernel<<<dim3(bc * 64), 256, 0, stream>>>(
            qh_ws, kh_ws, vt_ws, mTg, att_ws);
        gemm_proj<<<dim3(bc * 32 * 4), 256, 0, stream>>>(
            att_ws, wp, proj_b, outc);
    }
}